// Round 1
// baseline (174.311 us; speedup 1.0000x reference)
//
#include <hip/hip_runtime.h>

// HybridQuantumNetQML: fused quanvolution (2x2 patches -> cos features) +
// qfc + 2-class sampler softmax + 787x10 linear + log_softmax.
//
// Layout: block = 256 threads = 4 waves. Wave w ("sub") handles patches
// p = 4*q + w, q=0..48, for the 64 samples (one per lane) of this block.
// All W/bias/sampler-weight indices are wave-uniform (sub forced into an
// SGPR via readfirstlane) so the compiler emits scalar loads for W.
// Partial acc[10] reduced across the 4 waves through LDS; wave 0 runs the
// epilogue and stores 10 floats per sample.

__global__ __launch_bounds__(256, 2)
void qml_kernel(const float* __restrict__ x,
                const float* __restrict__ w,      // (787, 10) row-major
                const float* __restrict__ bias,   // (10,)
                const float* __restrict__ sw,     // (4,)
                float* __restrict__ out,          // (B, 10)
                int B)
{
    const int lane = threadIdx.x & 63;
    // wave id within block, forced wave-uniform (SGPR) so W addressing scalarizes
    const int sub = __builtin_amdgcn_readfirstlane((int)(threadIdx.x >> 6));

    int sample = blockIdx.x * 64 + lane;
    const bool active = (sample < B);
    if (sample >= B) sample = B - 1;   // clamp for safe loads; store is guarded

    const float* __restrict__ xrow = x + (size_t)sample * 784;

    float acc[10];
#pragma unroll
    for (int c = 0; c < 10; ++c) acc[c] = 0.0f;

    // qfeat[0..3] (patch 0 features) — produced by sub==0 at q==0
    float qf0 = 0.f, qf1 = 0.f, qf2 = 0.f, qf3 = 0.f;

    // patch p = 4*q + sub ; i = p/14, j = p%14 maintained incrementally (all scalar)
    int i = 0, j = sub;
    int wofs = 40 * sub;               // w row offset in floats: 10 * (4*p) = 160q + 40*sub

    for (int q = 0; q < 49; ++q) {
        const int off = (2 * i) * 28 + 2 * j;
        const float2 a01 = *(const float2*)(xrow + off);        // row 2i:   x[2i,2j], x[2i,2j+1]
        const float2 a23 = *(const float2*)(xrow + off + 28);   // row 2i+1: x[2i+1,2j], x[2i+1,2j+1]

        const float c0 = __cosf(a01.x);
        const float c1 = __cosf(a01.y);
        const float c2 = __cosf(a23.x);
        const float c3 = __cosf(a23.y);
        const float v0 = c0;
        const float v1 = c0 * c1;
        const float v2 = c2;
        const float v3 = c2 * c3;

        if (sub == 0 && q == 0) { qf0 = v0; qf1 = v1; qf2 = v2; qf3 = v3; }

        const float* __restrict__ wr = w + wofs;   // uniform address -> s_load
#pragma unroll
        for (int c = 0; c < 10; ++c) {
            acc[c] += v0 * wr[c] + v1 * wr[10 + c] + v2 * wr[20 + c] + v3 * wr[30 + c];
        }

        wofs += 160;
        j += 4;
        if (j >= 14) { j -= 14; i += 1; }
    }

    // ---- cross-wave reduction (4 subs -> wave 0) ----
    __shared__ float red[3][64][10];
    if (sub != 0) {
#pragma unroll
        for (int c = 0; c < 10; ++c) red[sub - 1][lane][c] = acc[c];
    }
    __syncthreads();

    if (sub == 0) {
#pragma unroll
        for (int c = 0; c < 10; ++c)
            acc[c] += red[0][lane][c] + red[1][lane][c] + red[2][lane][c];

        // ---- qfc: fully_connected_circuit on qfeat[:4] ----
        const float cf0 = __cosf(qf0);
        const float cf1 = __cosf(qf1);
        const float cf2 = __cosf(qf2);
        const float cf3 = __cosf(qf3);
        const float qfc = (cf0 + cf0 * cf1 + cf2 + cf2 * cf3) * 0.25f;

        // ---- sampler: softmax([z0, z1]) ----
        const float t0 = qf0 + sw[0] + sw[2];
        const float t1 = qf1 + sw[1] + sw[3];
        const float z0 = __cosf(t0);
        const float z1 = z0 * __cosf(t1);
        const float e0 = __expf(z0);
        const float e1 = __expf(z1);
        const float inv = 1.0f / (e0 + e1);
        const float s0 = e0 * inv;
        const float s1 = e1 * inv;

        // ---- tail rows of W (784: qfc, 785: s0, 786: s1) + bias ----
        const float* __restrict__ wt = w + 7840;   // uniform -> s_load
#pragma unroll
        for (int c = 0; c < 10; ++c)
            acc[c] += qfc * wt[c] + s0 * wt[10 + c] + s1 * wt[20 + c] + bias[c];

        // ---- log_softmax over 10 logits ----
        float m = acc[0];
#pragma unroll
        for (int c = 1; c < 10; ++c) m = fmaxf(m, acc[c]);
        float ssum = 0.0f;
#pragma unroll
        for (int c = 0; c < 10; ++c) ssum += __expf(acc[c] - m);
        const float lse = __logf(ssum) + m;

        if (active) {
            float* __restrict__ orow = out + (size_t)sample * 10;
#pragma unroll
            for (int c = 0; c < 10; ++c) orow[c] = acc[c] - lse;
        }
    }
}

extern "C" void kernel_launch(void* const* d_in, const int* in_sizes, int n_in,
                              void* d_out, int out_size, void* d_ws, size_t ws_size,
                              hipStream_t stream) {
    const float* x    = (const float*)d_in[0];   // (B,1,28,28) f32
    const float* w    = (const float*)d_in[1];   // (787,10)    f32
    const float* bias = (const float*)d_in[2];   // (10,)       f32
    const float* sw   = (const float*)d_in[3];   // (4,)        f32
    float* out = (float*)d_out;                  // (B,10)      f32

    const int B = in_sizes[0] / 784;
    const int blocks = (B + 63) / 64;
    qml_kernel<<<blocks, 256, 0, stream>>>(x, w, bias, sw, out, B);
}